// Round 6
// baseline (1589.541 us; speedup 1.0000x reference)
//
#include <hip/hip_runtime.h>

typedef _Float16 f16;
typedef _Float16 f16x8 __attribute__((ext_vector_type(8)));
typedef _Float16 f16x4 __attribute__((ext_vector_type(4)));
typedef float    f32x4 __attribute__((ext_vector_type(4)));

#define NB 4
#define SEQ 4096
#define DIM 512
#define MTOT (NB*SEQ)   // 16384
#define NEL ((size_t)MTOT*DIM)

// ---------------------------------------------------------------------------
// Projection GEMM: out[m,n] = f16( sum_k A[m,k] * W[n,k] + bias[n] )
// p: 0:q natural  1:qv natural  2:k K16-swizzled  3:kv V16-swizzled
// K16 (per batch, per 16-row kv tile t16, unit = 8 f16 along d):
//   unit = t16*1024 + n*64 + (((d>>3) + n) & 63), elem d&7;  n = s&15
// V16: unit = t16*1024 + chunk*512 + dl*2 + ((rh + (dl>>2)) & 1), elem r&7
//   r = s&15, rh = r>>3, chunk = d>>8, dl = d&255
// Both are contiguous 16KB spans per tile (DMA/stage-friendly) and give
// conflict-free (<=2-way) LDS frag reads in the attention kernel.
// ---------------------------------------------------------------------------
__global__ __launch_bounds__(256) void proj_gemm(
    const float* __restrict__ x, const float* __restrict__ y,
    const float* __restrict__ Wq, const float* __restrict__ bq,
    const float* __restrict__ Wqv, const float* __restrict__ bqv,
    const float* __restrict__ Wk, const float* __restrict__ bk,
    const float* __restrict__ Wkv, const float* __restrict__ bkv,
    f16* __restrict__ qh, f16* __restrict__ qvh,
    f16* __restrict__ kS, f16* __restrict__ vS)
{
    __shared__ __attribute__((aligned(16))) f16 a_lds[128][40];
    __shared__ __attribute__((aligned(16))) f16 b_lds[128][40];

    const int p = blockIdx.z;
    const float* A    = (p < 2) ? x : y;
    const float* W    = (p==0)?Wq:(p==1)?Wqv:(p==2)?Wk:Wkv;
    const float* bias = (p==0)?bq:(p==1)?bqv:(p==2)?bk:bkv;

    const int m0 = blockIdx.y * 128, n0 = blockIdx.x * 128;
    const int tid = threadIdx.x, lane = tid & 63, wv = tid >> 6;
    const int wm = wv >> 1, wn = wv & 1, mrow = lane & 15, qd = lane >> 4;

    f32x4 acc[4][4];
#pragma unroll
    for (int mt = 0; mt < 4; ++mt)
#pragma unroll
        for (int nt = 0; nt < 4; ++nt) acc[mt][nt] = (f32x4){0.f,0.f,0.f,0.f};

    float bv[4];
#pragma unroll
    for (int nt = 0; nt < 4; ++nt) bv[nt] = bias[n0 + wn*64 + nt*16 + mrow];

    for (int k0 = 0; k0 < DIM; k0 += 32) {
        __syncthreads();
#pragma unroll
        for (int i = 0; i < 4; ++i) {
            int c = i*256 + tid;
            int row = c >> 3, c4 = c & 7;
            float4 v = *(const float4*)(A + (size_t)(m0+row)*DIM + k0 + c4*4);
            f16x4 hh = { (f16)v.x, (f16)v.y, (f16)v.z, (f16)v.w };
            *(f16x4*)&a_lds[row][c4*4] = hh;
        }
#pragma unroll
        for (int i = 0; i < 4; ++i) {
            int c = i*256 + tid;
            int row = c >> 3, c4 = c & 7;
            float4 v = *(const float4*)(W + (size_t)(n0+row)*DIM + k0 + c4*4);
            f16x4 hh = { (f16)v.x, (f16)v.y, (f16)v.z, (f16)v.w };
            *(f16x4*)&b_lds[row][c4*4] = hh;
        }
        __syncthreads();
        f16x8 af[4], bfr[4];
#pragma unroll
        for (int mt = 0; mt < 4; ++mt) af[mt]  = *(const f16x8*)&a_lds[wm*64 + mt*16 + mrow][qd*8];
#pragma unroll
        for (int nt = 0; nt < 4; ++nt) bfr[nt] = *(const f16x8*)&b_lds[wn*64 + nt*16 + mrow][qd*8];
#pragma unroll
        for (int mt = 0; mt < 4; ++mt)
#pragma unroll
            for (int nt = 0; nt < 4; ++nt)
                acc[mt][nt] = __builtin_amdgcn_mfma_f32_16x16x32_f16(af[mt], bfr[nt], acc[mt][nt], 0,0,0);
    }

#pragma unroll
    for (int mt = 0; mt < 4; ++mt)
#pragma unroll
        for (int r = 0; r < 4; ++r) {
            int g = m0 + wm*64 + mt*16 + qd*4 + r;
#pragma unroll
            for (int nt = 0; nt < 4; ++nt) {
                int d = n0 + wn*64 + nt*16 + mrow;
                f16 val = (f16)(acc[mt][nt][r] + bv[nt]);
                if (p == 0) {
                    qh[(size_t)g*DIM + d] = val;
                } else if (p == 1) {
                    qvh[(size_t)g*DIM + d] = val;
                } else if (p == 2) {
                    int b = g >> 12, s = g & 4095;
                    int t16 = s >> 4, n = s & 15;
                    size_t idx = (((size_t)(b*256 + t16)*1024
                                   + n*64 + (((d >> 3) + n) & 63)) << 3) + (d & 7);
                    kS[idx] = val;
                } else {
                    int b = g >> 12, s = g & 4095;
                    int t16 = s >> 4, r16 = s & 15, rh = r16 >> 3;
                    int chunk = d >> 8, dl = d & 255;
                    size_t idx = (((size_t)(b*256 + t16)*1024
                                   + chunk*512 + dl*2 + ((rh + (dl >> 2)) & 1)) << 3) + (r16 & 7);
                    vS[idx] = val;
                }
            }
        }
}

// ---------------------------------------------------------------------------
// Flash attention: kv-split + L2 swizzle + double-buffered 1-barrier pipeline.
// 512 blocks, 256 thr (4 waves x 16 Q rows), each sweeps HALF of KV (2048
// rows = 128 iters of 16-row tiles). xcd = bx&7 -> (batch, half): each XCD's
// 32 blocks share a 4MB K+V working set (L2-resident). 2 blocks/CU
// (LDS 66.5KB) -> 8 waves/CU. QK^T: 16x16x32; PV: 16x16x16 (K matches tile).
// ---------------------------------------------------------------------------
__global__ __launch_bounds__(256, 2) void attn_kernel(
    const f16* __restrict__ qh, const f16* __restrict__ kS,
    const f16* __restrict__ vS, f16* __restrict__ opart,
    float* __restrict__ ml)
{
    __shared__ __attribute__((aligned(16))) f16 kbuf[2][8192];  // 2 x 16KB
    __shared__ __attribute__((aligned(16))) f16 vbuf[2][8192];  // 2 x 16KB
    __shared__ __attribute__((aligned(16))) f16 p_lds[4][16][20];

    const int bx  = blockIdx.x;
    const int xcd = bx & 7;
    const int b   = xcd >> 1;
    const int h   = xcd & 1;
    const int qt  = bx >> 3;                 // 0..63
    const int tid = threadIdx.x, lane = tid & 63, w = tid >> 6;
    const int mrow = lane & 15, qd = lane >> 4;

    const f16* kSb = kS + ((size_t)(b*256 + h*128) << 13);  // *1024 units *8
    const f16* vSb = vS + ((size_t)(b*256 + h*128) << 13);

    // Q fragments (A-layout): lane m+16q holds Q[m][32*ks + 8q + j]
    const size_t qrow = ((size_t)b*SEQ + qt*64 + w*16 + mrow) * DIM;
    f16x8 qf[16];
#pragma unroll
    for (int ks = 0; ks < 16; ++ks)
        qf[ks] = *(const f16x8*)(qh + qrow + ks*32 + qd*8);

    f32x4 o[32];
#pragma unroll
    for (int nt = 0; nt < 32; ++nt) o[nt] = (f32x4){0.f,0.f,0.f,0.f};
    f32x4 o_l = (f32x4){0.f,0.f,0.f,0.f};
    float m_i[4] = {-INFINITY,-INFINITY,-INFINITY,-INFINITY};
    const f16x4 ones4 = {(f16)1.f,(f16)1.f,(f16)1.f,(f16)1.f};

    f16x8 sk[4], sv[4];
    // prologue: stage tile 0 into buf 0
#pragma unroll
    for (int j = 0; j < 4; ++j) {
        sk[j] = *(const f16x8*)(kSb + (j*256 + tid)*8);
        sv[j] = *(const f16x8*)(vSb + (j*256 + tid)*8);
    }
#pragma unroll
    for (int j = 0; j < 4; ++j) {
        *(f16x8*)&kbuf[0][(j*256 + tid)*8] = sk[j];
        *(f16x8*)&vbuf[0][(j*256 + tid)*8] = sv[j];
    }
    __syncthreads();

    for (int i = 0; i < 128; ++i) {
        // prefetch next tile's loads NOW; consumed after ~2000 cyc of compute
        const int nxt = (i < 127) ? i + 1 : i;
        const f16* kt = kSb + (size_t)nxt*8192;
        const f16* vt = vSb + (size_t)nxt*8192;
#pragma unroll
        for (int j = 0; j < 4; ++j) {
            sk[j] = *(const f16x8*)(kt + (j*256 + tid)*8);
            sv[j] = *(const f16x8*)(vt + (j*256 + tid)*8);
        }

        const f16* kb = &kbuf[i & 1][0];
        const f16* vb = &vbuf[i & 1][0];

        // S = Q K^T : 16 q-rows x 16 kv-cols per wave; 2 independent chains
        f32x4 sA = (f32x4){0.f,0.f,0.f,0.f}, sB = sA;
#pragma unroll
        for (int ks = 0; ks < 16; ks += 2) {
            f16x8 kf0 = *(const f16x8*)&kb[(mrow*64 + ((ks*4 + qd + mrow) & 63)) << 3];
            f16x8 kf1 = *(const f16x8*)&kb[(mrow*64 + (((ks+1)*4 + qd + mrow) & 63)) << 3];
            sA = __builtin_amdgcn_mfma_f32_16x16x32_f16(qf[ks],   kf0, sA, 0,0,0);
            sB = __builtin_amdgcn_mfma_f32_16x16x32_f16(qf[ks+1], kf1, sB, 0,0,0);
        }
        f32x4 s0;
#pragma unroll
        for (int rr = 0; rr < 4; ++rr) s0[rr] = sA[rr] + sB[rr];

        // online softmax (row r = 4*qd+rr across quad's 16 lanes)
        float alpha[4];
        bool changed = false;
#pragma unroll
        for (int rr = 0; rr < 4; ++rr) {
            float v = s0[rr];
            v = fmaxf(v, __shfl_xor(v, 1));
            v = fmaxf(v, __shfl_xor(v, 2));
            v = fmaxf(v, __shfl_xor(v, 4));
            v = fmaxf(v, __shfl_xor(v, 8));
            float mn = fmaxf(m_i[rr], v);
            alpha[rr] = __expf(m_i[rr] - mn);
            if (mn > m_i[rr]) changed = true;
            m_i[rr] = mn;
            s0[rr] = __expf(s0[rr] - mn);
        }
        if (__any(changed)) {
#pragma unroll
            for (int nt = 0; nt < 32; ++nt)
#pragma unroll
                for (int rr = 0; rr < 4; ++rr) o[nt][rr] *= alpha[rr];
#pragma unroll
            for (int rr = 0; rr < 4; ++rr) o_l[rr] *= alpha[rr];
        }

        // P: C-layout -> A-layout (16x16) via per-wave LDS
#pragma unroll
        for (int rr = 0; rr < 4; ++rr)
            p_lds[w][qd*4 + rr][mrow] = (f16)s0[rr];
        f16x4 pf = *(const f16x4*)&p_lds[w][mrow][qd*4];
        o_l = __builtin_amdgcn_mfma_f32_16x16x16f16(pf, ones4, o_l, 0,0,0);

        // O += P @ V : 32 d-tiles, K=16 (full kv tile per MFMA)
#pragma unroll
        for (int nt = 0; nt < 32; ++nt) {
            int d = nt*16 + mrow;
            int chunk = nt >> 4, dl = d & 255;
            int u = chunk*512 + dl*2 + (((qd >> 1) + (dl >> 2)) & 1);
            f16x4 vf = *(const f16x4*)&vb[(u << 3) + (qd & 1)*4];
            o[nt] = __builtin_amdgcn_mfma_f32_16x16x16f16(pf, vf, o[nt], 0,0,0);
        }

        // write next tile into the other buffer; barrier closes the iter
        f16* kw = &kbuf[(i + 1) & 1][0];
        f16* vw = &vbuf[(i + 1) & 1][0];
#pragma unroll
        for (int j = 0; j < 4; ++j) {
            *(f16x8*)&kw[(j*256 + tid)*8] = sk[j];
            *(f16x8*)&vw[(j*256 + tid)*8] = sv[j];
        }
        __syncthreads();
    }

    // epilogue: normalized partial O + (m,l)
    float inv_l[4];
#pragma unroll
    for (int rr = 0; rr < 4; ++rr) inv_l[rr] = 1.f / o_l[rr];
#pragma unroll
    for (int rr = 0; rr < 4; ++rr) {
        size_t grow = ((size_t)b*SEQ + qt*64 + w*16 + qd*4 + rr) * DIM;
#pragma unroll
        for (int nt = 0; nt < 32; ++nt) {
            int col = nt*16 + mrow;
            opart[(size_t)h*NEL + grow + col] = (f16)(o[nt][rr] * inv_l[rr]);
        }
    }
    if (mrow == 0) {
#pragma unroll
        for (int rr = 0; rr < 4; ++rr) {
            int idx = (h << 14) + b*SEQ + qt*64 + w*16 + qd*4 + rr;
            ml[idx*2 + 0] = m_i[rr];
            ml[idx*2 + 1] = o_l[rr];
        }
    }
}

// ---------------------------------------------------------------------------
// Merge the two kv-half partials (LSE-weighted) + qv residual -> ao (f16)
// ---------------------------------------------------------------------------
__global__ __launch_bounds__(256) void merge_kernel(
    const f16* __restrict__ opart, const float* __restrict__ ml,
    const f16* __restrict__ qvh, f16* __restrict__ ao)
{
    int gid = blockIdx.x * 256 + threadIdx.x;
    int row = gid >> 6;
    int dc  = (gid & 63) * 8;
    float m1 = ml[row*2 + 0],           l1 = ml[row*2 + 1];
    float m2 = ml[(row + MTOT)*2 + 0],  l2 = ml[(row + MTOT)*2 + 1];
    float mm = fmaxf(m1, m2);
    float w1 = __expf(m1 - mm) * l1, w2 = __expf(m2 - mm) * l2;
    float il = 1.f / (w1 + w2);
    w1 *= il; w2 *= il;
    f16x8 o1 = *(const f16x8*)(opart + (size_t)row*DIM + dc);
    f16x8 o2 = *(const f16x8*)(opart + NEL + (size_t)row*DIM + dc);
    f16x8 qv = *(const f16x8*)(qvh + (size_t)row*DIM + dc);
    f16x8 r;
#pragma unroll
    for (int j = 0; j < 8; ++j)
        r[j] = (f16)(w1*(float)o1[j] + w2*(float)o2[j] + (float)qv[j]);
    *(f16x8*)(ao + (size_t)row*DIM + dc) = r;
}

// ---------------------------------------------------------------------------
// Final linear: out[m,n] = sum_k ao[m,k]*Wf[n,k] + bf[n]  (f32 out)
// ---------------------------------------------------------------------------
__global__ __launch_bounds__(256) void final_gemm(
    const f16* __restrict__ ao, const float* __restrict__ Wf,
    const float* __restrict__ bf, float* __restrict__ out)
{
    __shared__ __attribute__((aligned(16))) f16 a_lds[128][40];
    __shared__ __attribute__((aligned(16))) f16 b_lds[128][40];

    const int m0 = blockIdx.y * 128, n0 = blockIdx.x * 128;
    const int tid = threadIdx.x, lane = tid & 63, wv = tid >> 6;
    const int wm = wv >> 1, wn = wv & 1, mrow = lane & 15, qd = lane >> 4;

    f32x4 acc[4][4];
#pragma unroll
    for (int mt = 0; mt < 4; ++mt)
#pragma unroll
        for (int nt = 0; nt < 4; ++nt) acc[mt][nt] = (f32x4){0.f,0.f,0.f,0.f};

    float bv[4];
#pragma unroll
    for (int nt = 0; nt < 4; ++nt) bv[nt] = bf[n0 + wn*64 + nt*16 + mrow];

    for (int k0 = 0; k0 < DIM; k0 += 32) {
        __syncthreads();
#pragma unroll
        for (int i = 0; i < 2; ++i) {
            int c = i*256 + tid;
            int row = c >> 2, c8 = c & 3;
            *(f16x8*)&a_lds[row][c8*8] =
                *(const f16x8*)(ao + (size_t)(m0+row)*DIM + k0 + c8*8);
        }
#pragma unroll
        for (int i = 0; i < 4; ++i) {
            int c = i*256 + tid;
            int row = c >> 3, c4 = c & 7;
            float4 v = *(const float4*)(Wf + (size_t)(n0+row)*DIM + k0 + c4*4);
            f16x4 hh = { (f16)v.x, (f16)v.y, (f16)v.z, (f16)v.w };
            *(f16x4*)&b_lds[row][c4*4] = hh;
        }
        __syncthreads();
        f16x8 af[4], bfr[4];
#pragma unroll
        for (int mt = 0; mt < 4; ++mt) af[mt]  = *(const f16x8*)&a_lds[wm*64 + mt*16 + mrow][qd*8];
#pragma unroll
        for (int nt = 0; nt < 4; ++nt) bfr[nt] = *(const f16x8*)&b_lds[wn*64 + nt*16 + mrow][qd*8];
#pragma unroll
        for (int mt = 0; mt < 4; ++mt)
#pragma unroll
            for (int nt = 0; nt < 4; ++nt)
                acc[mt][nt] = __builtin_amdgcn_mfma_f32_16x16x32_f16(af[mt], bfr[nt], acc[mt][nt], 0,0,0);
    }
#pragma unroll
    for (int mt = 0; mt < 4; ++mt)
#pragma unroll
        for (int r = 0; r < 4; ++r) {
            size_t grow = (size_t)(m0 + wm*64 + mt*16 + qd*4 + r) * DIM;
#pragma unroll
            for (int nt = 0; nt < 4; ++nt) {
                int col = n0 + wn*64 + nt*16 + mrow;
                out[grow + col] = acc[mt][nt][r] + bv[nt];
            }
        }
}

// ---------------------------------------------------------------------------
extern "C" void kernel_launch(void* const* d_in, const int* in_sizes, int n_in,
                              void* d_out, int out_size, void* d_ws, size_t ws_size,
                              hipStream_t stream)
{
    const float* x   = (const float*)d_in[0];
    const float* y   = (const float*)d_in[1];
    const float* Wq  = (const float*)d_in[2];
    const float* bq  = (const float*)d_in[3];
    const float* Wqv = (const float*)d_in[4];
    const float* bqv = (const float*)d_in[5];
    const float* Wk  = (const float*)d_in[6];
    const float* bk  = (const float*)d_in[7];
    const float* Wkv = (const float*)d_in[8];
    const float* bkv = (const float*)d_in[9];
    const float* Wf  = (const float*)d_in[10];
    const float* bf  = (const float*)d_in[11];
    float* out = (float*)d_out;

    f16* qh    = (f16*)d_ws;       // NEL f16 each
    f16* qvh   = qh  + NEL;
    f16* kS    = qvh + NEL;
    f16* vS    = kS  + NEL;
    f16* opart = vS  + NEL;        // 2*NEL
    float* ml  = (float*)(opart + 2*NEL);  // 2*MTOT*2 floats
    f16* aob   = kS;               // alias: kS dead after attn_kernel

    proj_gemm<<<dim3(4, 128, 4), 256, 0, stream>>>(
        x, y, Wq, bq, Wqv, bqv, Wk, bk, Wkv, bkv, qh, qvh, kS, vS);
    attn_kernel<<<dim3(512), 256, 0, stream>>>(qh, kS, vS, opart, ml);
    merge_kernel<<<dim3(4096), 256, 0, stream>>>(opart, ml, qvh, aob);
    final_gemm<<<dim3(4, 128), 256, 0, stream>>>(aob, Wf, bf, out);
}